// Round 9
// baseline (285.554 us; speedup 1.0000x reference)
//
#include <hip/hip_runtime.h>

// Retention, B=4 S=4096 H=1024, gamma=0.96875.
// out[b,i,:] = sum_{j<=i} gamma^(i-j) * (q_i . k_j) * v_j
//
// Pipeline (all bf16 MFMA GEMMs, 128x128 tile, BK=64 double-half staging, XCD-swizzled grids):
//   x~   = [x | 1 | 0pad63]               (16384 x 1088 bf16)
//   W~qT = [Wq^T ; bq ; 0pad]             (1152 x 1024 bf16)   (same for k)
//   P1   = W~kT . W~qT^T                  (1152 x 1088)
//   G    = x~ . P1^T = x~ M~              (16384 x 1088)
//   Vt   = (Wv . x~^T) scattered          ([b][h][s] bf16)
//   Pb   = band(G . x~^T) * gamma^d       (128 qtiles x 128 x 384 bf16)
//   out  = Pb . Vt^T (banded K<=384)      (f32)
// Band window 256..383; truncated tail std ~0.04 << tol 6.0.
//
// R9 = R8 resubmitted (R8 bench hit an infra failure: "MI355X container failed
// twice", no kernel error).  R8 change recap: counters showed VALUBusy (27.5%)
// ~= MfmaUtil (26.3%) on every GEMM — the signature of per-K-step address
// recomputation (runtime lda -> 64-bit mul/add chains, ~50-60 VALU
// ops/thread/step vs ~160 cyc of MFMA issue).  Fix: (1) strides as template
// constants (LDA/LDW/LDO), (2) staging pointers hoisted out of the K-loop —
// 8 gload_lds + four "+= 64" per step instead of 8 full address builds,
// (3) MODE 2 decay factorized gamma^(D0+row)*gamma^(-col) (20 exp2f vs 64).
// Grids/fusion/band identical to R7 (best measured: 281 us).

typedef __attribute__((ext_vector_type(8))) short short8;   // 8 bf16 = 4 VGPRs
typedef __attribute__((ext_vector_type(4))) float floatx4;  // MFMA 16x16 C/D

#define MFMA(a, b, c) __builtin_amdgcn_mfma_f32_16x16x32_bf16((a), (b), (c), 0, 0, 0)

#define B_SZ   4
#define S_LEN  4096
#define H_DIM  1024
#define NROWS  (B_SZ * S_LEN)          // 16384
#define HP     1088                    // padded H+1 (17*64)
#define WR     1152                    // padded weight rows (9*128)
#define KB3    384                     // band width (3 slots of 128)
#define LOG2G  (-0.045803690f)         // log2(0.96875)

__device__ __forceinline__ unsigned short f32_to_bf16_rn(float f) {
    unsigned int u = __float_as_uint(f);
    u += 0x7FFFu + ((u >> 16) & 1u);   // round-to-nearest-even
    return (unsigned short)(u >> 16);
}

#define GLOAD_LDS16(gptr, lptr)                                                        \
    __builtin_amdgcn_global_load_lds((__attribute__((address_space(1))) void*)(gptr),  \
                                     (__attribute__((address_space(3))) void*)(lptr),  \
                                     16, 0, 0)

// ---------------------------------------------------------------- elementwise bodies
__device__ __forceinline__ void cvt_bf16_body(int i, const float* __restrict__ src,
                                              unsigned short* __restrict__ dst, int n4) {
    if (i >= n4) return;
    float4 v = ((const float4*)src)[i];
    ushort4 o;
    o.x = f32_to_bf16_rn(v.x);
    o.y = f32_to_bf16_rn(v.y);
    o.z = f32_to_bf16_rn(v.z);
    o.w = f32_to_bf16_rn(v.w);
    ((ushort4*)dst)[i] = o;
}

// x -> x~ rows of HP (cols 0..1023)
__device__ __forceinline__ void cvt_x_body(int idx, const float* __restrict__ src,
                                           unsigned short* __restrict__ dst) {
    int row = idx >> 7, c8 = (idx & 127) * 8;
    const float4* s = (const float4*)(src + (size_t)row * H_DIM + c8);
    float4 a = s[0], b = s[1];
    ushort4 o0, o1;
    o0.x = f32_to_bf16_rn(a.x); o0.y = f32_to_bf16_rn(a.y);
    o0.z = f32_to_bf16_rn(a.z); o0.w = f32_to_bf16_rn(a.w);
    o1.x = f32_to_bf16_rn(b.x); o1.y = f32_to_bf16_rn(b.y);
    o1.z = f32_to_bf16_rn(b.z); o1.w = f32_to_bf16_rn(b.w);
    ushort4* d = (ushort4*)(dst + (size_t)row * HP + c8);
    d[0] = o0; d[1] = o1;
}

// cols 1024..1087 of x~: 1.0 at col 1024, zeros elsewhere
__device__ __forceinline__ void fill_pad_body(int idx, unsigned short* __restrict__ dst) {
    int row = idx >> 3, c = idx & 7;
    uint4 v; v.x = (c == 0) ? 0x00003F80u : 0u; v.y = 0u; v.z = 0u; v.w = 0u;
    *(uint4*)(dst + (size_t)row * HP + 1024 + c * 8) = v;
}

// W (f32) + bias -> [W^T ; bias ; 0] bf16, 1152x1024.  (bx in [0,8), by in [0,36))
__device__ __forceinline__ void tr_cvt_body(float (&Lt)[128][33],
                                            const float* __restrict__ Wsrc,
                                            const float* __restrict__ bias,
                                            unsigned short* __restrict__ dst,
                                            int bx, int by, int tid) {
    if (by >= 32) {                                // rows 1024..1151: bias row + zeros
        if (bx != 0) return;
        const int h0 = by * 32;
#pragma unroll
        for (int i = 0; i < 128; ++i) {
            int idx = i * 256 + tid;               // 32*1024
            int r = idx >> 10, cc = idx & 1023;
            int h = h0 + r;
            float v = (h == 1024) ? bias[cc] : 0.0f;
            dst[(size_t)h * 1024 + cc] = f32_to_bf16_rn(v);
        }
        return;
    }
    const int w0 = bx * 128, h0 = by * 32;
#pragma unroll
    for (int i = 0; i < 16; ++i) {
        int idx = i * 256 + tid;
        int r = idx >> 5, cc = idx & 31;
        Lt[r][cc] = Wsrc[(size_t)(w0 + r) * 1024 + h0 + cc];
    }
    __syncthreads();
#pragma unroll
    for (int i = 0; i < 16; ++i) {
        int idx = i * 256 + tid;
        int hh = idx >> 7, ww = idx & 127;
        dst[(size_t)(h0 + hh) * 1024 + w0 + ww] = f32_to_bf16_rn(Lt[ww][hh]);
    }
}

// ---------------------------------------------------------------- generic 128x128 MFMA GEMM body
// C[n,o] = sum_k A[n,k]*W[o,k].  BK=64 as two 32-halves (32 KB LDS), 2 barriers / 64K.
// Strides are template constants; staging pointers hoisted (4x "+=64"/step).
// MODE 0: bf16 row-major store (col-clip p0)   MODE 1: Vt scatter (by=xtile, bx=htile)
// MODE 2: decay epilogue -> Pb band (3 slots)  MODE 3: banded-K (<=384), f32 store
template <int MODE, int LDA, int LDW, int LDO>
__device__ __forceinline__ void gemm_body(unsigned short (&As)[2][128 * 32],
                                          unsigned short (&Bs)[2][128 * 32],
                                          int bx, int by,
                                          const unsigned short* __restrict__ A,
                                          const unsigned short* __restrict__ W,
                                          void* __restrict__ outp, int K, int p0) {
    const int tid  = threadIdx.x;
    const int lane = tid & 63;
    const int w4   = tid >> 6;
    const int wm   = w4 >> 1, wn = w4 & 1;
    const int l15  = lane & 15;
    const int q8   = (lane >> 4) * 8;
    const int q4   = (lane >> 4) * 4;

    int aRow0 = 0, wRow0 = 0, kStart = 0;
    const unsigned short* Ap = A;
    const unsigned short* Wp = W;
    const int tT = by;
    const int tl = tT & 31;
    int jt = 0;

    if (MODE == 0) {
        aRow0 = by * 128; wRow0 = bx * 128;
    } else if (MODE == 1) {
        aRow0 = bx * 128; wRow0 = by * 128;       // bx=h-tile, by=x-row-tile (localized)
    } else if (MODE == 2) {
        jt = tl - 2 + bx;
        if (jt < 0) return;                        // block-uniform early exit
        aRow0 = tT * 128;
        wRow0 = (tT >> 5) * S_LEN + jt * 128;
    } else {                                       // MODE 3
        kStart = (tl < 2) ? (2 - tl) * 128 : 0;
        Ap = A + (size_t)tT * 128 * KB3;
        Wp = W + (size_t)((tT >> 5) * H_DIM + bx * 128) * S_LEN + (ptrdiff_t)(tl - 2) * 128;
    }

    floatx4 acc[4][4];
#pragma unroll
    for (int i = 0; i < 4; ++i)
#pragma unroll
        for (int j = 0; j < 4; ++j) acc[i][j] = (floatx4)0.0f;

    // hoisted staging addresses: chunk c0 = tid (p=0), c1 = 256+tid (p=1);
    // row = c>>2, 8-elem chunk = c&3.  Advance by 64 elems (128 B) per K-step.
    const int c0 = tid, c1 = 256 + tid;
    const unsigned short* gA0 = Ap + (size_t)(aRow0 + (c0 >> 2)) * LDA + kStart + (c0 & 3) * 8;
    const unsigned short* gA1 = Ap + (size_t)(aRow0 + (c1 >> 2)) * LDA + kStart + (c1 & 3) * 8;
    const unsigned short* gW0 = Wp + (size_t)(wRow0 + (c0 >> 2)) * LDW + kStart + (c0 & 3) * 8;
    const unsigned short* gW1 = Wp + (size_t)(wRow0 + (c1 >> 2)) * LDW + kStart + (c1 & 3) * 8;
    char* const dA00 = (char*)&As[0][0] + (size_t)(w4 * 64) * 16;   // p=0, half 0
    char* const dA10 = (char*)&As[1][0] + (size_t)(w4 * 64) * 16;   // p=0, half 1
    char* const dA01 = dA00 + 256 * 16;                             // p=1, half 0
    char* const dA11 = dA10 + 256 * 16;                             // p=1, half 1
    char* const dB00 = (char*)&Bs[0][0] + (size_t)(w4 * 64) * 16;
    char* const dB10 = (char*)&Bs[1][0] + (size_t)(w4 * 64) * 16;
    char* const dB01 = dB00 + 256 * 16;
    char* const dB11 = dB10 + 256 * 16;

    for (int k0 = kStart; k0 < K; k0 += 64) {
        __syncthreads();
        GLOAD_LDS16(gA0,      dA00);
        GLOAD_LDS16(gA0 + 32, dA10);
        GLOAD_LDS16(gA1,      dA01);
        GLOAD_LDS16(gA1 + 32, dA11);
        GLOAD_LDS16(gW0,      dB00);
        GLOAD_LDS16(gW0 + 32, dB10);
        GLOAD_LDS16(gW1,      dB01);
        GLOAD_LDS16(gW1 + 32, dB11);
        gA0 += 64; gA1 += 64; gW0 += 64; gW1 += 64;
        __syncthreads();

#pragma unroll
        for (int h = 0; h < 2; ++h) {
            short8 af[4], bf[4];
#pragma unroll
            for (int mt = 0; mt < 4; ++mt)
                af[mt] = *(const short8*)(&As[h][0] + (wm * 64 + mt * 16 + l15) * 32 + q8);
#pragma unroll
            for (int nt = 0; nt < 4; ++nt)
                bf[nt] = *(const short8*)(&Bs[h][0] + (wn * 64 + nt * 16 + l15) * 32 + q8);
#pragma unroll
            for (int mt = 0; mt < 4; ++mt)
#pragma unroll
                for (int nt = 0; nt < 4; ++nt)
                    acc[mt][nt] = MFMA(af[mt], bf[nt], acc[mt][nt]);
        }
    }

    // ---- epilogue (C/D layout: col=lane&15, row=(lane>>4)*4+r)
    float colf[4], rowf[4][4];
    if (MODE == 2) {
        const int D0 = (2 - bx) * 128;             // = (tl - jt) * 128
#pragma unroll
        for (int nt = 0; nt < 4; ++nt)
            colf[nt] = exp2f(-(float)(wn * 64 + nt * 16 + l15) * LOG2G);     // g^-col
#pragma unroll
        for (int mt = 0; mt < 4; ++mt)
#pragma unroll
            for (int r = 0; r < 4; ++r)
                rowf[mt][r] = exp2f((float)(D0 + wm * 64 + mt * 16 + q4 + r) * LOG2G);
    }
#pragma unroll
    for (int nt = 0; nt < 4; ++nt) {
        const int ol = wn * 64 + nt * 16 + l15;
#pragma unroll
        for (int mt = 0; mt < 4; ++mt) {
#pragma unroll
            for (int r = 0; r < 4; ++r) {
                const int nl = wm * 64 + mt * 16 + q4 + r;
                const float v = acc[mt][nt][r];
                if (MODE == 0) {
                    const int o = wRow0 + ol;
                    if (o < p0)
                        ((unsigned short*)outp)[(size_t)(aRow0 + nl) * LDO + o] = f32_to_bf16_rn(v);
                } else if (MODE == 1) {
                    const int s = wRow0 + ol;              // global x row
                    const int hh = aRow0 + nl;             // h
                    ((unsigned short*)outp)[((size_t)(s >> 12) * H_DIM + hh) * S_LEN + (s & (S_LEN - 1))] =
                        f32_to_bf16_rn(v);
                } else if (MODE == 2) {
                    const int d = (2 - bx) * 128 + nl - ol;
                    const float pv = (d >= 0) ? v * rowf[mt][r] * colf[nt] : 0.0f;
                    ((unsigned short*)outp)[(size_t)tT * (128 * KB3) + (size_t)nl * KB3 +
                                            (size_t)bx * 128 + ol] = f32_to_bf16_rn(pv);
                } else {                                   // MODE 3
                    ((float*)outp)[(size_t)(tT * 128 + nl) * LDO + bx * 128 + ol] = v;
                }
            }
        }
    }
}

// ---------------------------------------------------------------- fused launches
// L1: all prep (independent): tr_cvt(Wq), tr_cvt(Wk), cvt Wv, x~ pad cols
__global__ __launch_bounds__(256) void prep_small(const float* __restrict__ Wq,
                                                  const float* __restrict__ bq,
                                                  const float* __restrict__ Wk,
                                                  const float* __restrict__ bk,
                                                  const float* __restrict__ Wv,
                                                  unsigned short* __restrict__ wqT,
                                                  unsigned short* __restrict__ wkT,
                                                  unsigned short* __restrict__ wvb,
                                                  unsigned short* __restrict__ xtb) {
    __shared__ float Lt[128][33];
    const int t = blockIdx.x, tid = threadIdx.x;
    if (t < 288) {
        tr_cvt_body(Lt, Wq, bq, wqT, t & 7, t >> 3, tid);
    } else if (t < 576) {
        const int t2 = t - 288;
        tr_cvt_body(Lt, Wk, bk, wkT, t2 & 7, t2 >> 3, tid);
    } else if (t < 1600) {
        cvt_bf16_body((t - 576) * 256 + tid, Wv, wvb, H_DIM * H_DIM / 4);
    } else {
        fill_pad_body((t - 1600) * 256 + tid, xtb);
    }
}

// L2: P1 (81 latency-bound blocks, first) ∪ cvt_x (8192 streaming blocks hide it)
__global__ __launch_bounds__(256) void cvtx_p1(const float* __restrict__ x,
                                               unsigned short* __restrict__ xtb,
                                               const unsigned short* __restrict__ wkT,
                                               const unsigned short* __restrict__ wqT,
                                               unsigned short* __restrict__ p1) {
    __shared__ unsigned short As[2][128 * 32];
    __shared__ unsigned short Bs[2][128 * 32];
    const int t = blockIdx.x;
    if (t < 81) {
        // P1 = W~kT . W~qT^T  (1152 x 1088, K=1024)
        gemm_body<0, 1024, 1024, HP>(As, Bs, t % 9, t / 9, wkT, wqT, p1, 1024, HP);
    } else {
        cvt_x_body((t - 81) * 256 + threadIdx.x, x, xtb);
    }
}

// L3: G = x~ . P1^T  (16384 x 1088, K=1088), XCD-swizzled
__global__ __launch_bounds__(256) void gemm_g(const unsigned short* __restrict__ xtb,
                                              const unsigned short* __restrict__ p1,
                                              unsigned short* __restrict__ gb) {
    __shared__ unsigned short As[2][128 * 32];
    __shared__ unsigned short Bs[2][128 * 32];
    const int bid = blockIdx.x;
    const int g = bid & 7, j = bid >> 3;
    gemm_body<0, HP, HP, HP>(As, Bs, j % 9, g * 16 + j / 9, xtb, p1, gb, HP, HP);
}

// L4: Pb (384 blocks, latency-exposed — first) ∪ Vt (1024 throughput blocks behind).
// Both sub-ranges 8-aligned so bid&7 XCD swizzle holds.
__global__ __launch_bounds__(256) void pb_vt(const unsigned short* __restrict__ gb,
                                             const unsigned short* __restrict__ xtb,
                                             const unsigned short* __restrict__ wvb,
                                             unsigned short* __restrict__ pb,
                                             unsigned short* __restrict__ vtb) {
    __shared__ unsigned short As[2][128 * 32];
    __shared__ unsigned short Bs[2][128 * 32];
    const int t = blockIdx.x;
    if (t < 384) {
        // Pb = band(G . x~^T) * gamma^d  (3 slots per q-tile, K=1088)
        const int g = t & 7, j = t >> 3;        // 384 = 8 * 48
        gemm_body<2, HP, HP, KB3>(As, Bs, j % 3, g * 16 + j / 3, gb, xtb, pb, HP, 0);
    } else {
        // Vt = Wv . x~^T scattered to [b][h][s]  (K=1024)
        const int t2 = t - 384;
        const int g = t2 & 7, j = t2 >> 3;      // 1024 = 8 * 128
        gemm_body<1, 1024, HP, 1>(As, Bs, j & 7, g * 16 + (j >> 3), wvb, xtb, vtb, 1024, 0);
    }
}

// L5: out = Pb . Vt^T  (banded K<=384, f32)
__global__ __launch_bounds__(256) void gemm_out(const unsigned short* __restrict__ pb,
                                                const unsigned short* __restrict__ vtb,
                                                float* __restrict__ out) {
    __shared__ unsigned short As[2][128 * 32];
    __shared__ unsigned short Bs[2][128 * 32];
    const int bid = blockIdx.x;                 // 1024 = 8 * 128
    const int g = bid & 7, j = bid >> 3;
    gemm_body<3, KB3, S_LEN, H_DIM>(As, Bs, j & 7, g * 16 + (j >> 3), pb, vtb, out, KB3, 0);
}

// ---------------------------------------------------------------- launcher
extern "C" void kernel_launch(void* const* d_in, const int* in_sizes, int n_in,
                              void* d_out, int out_size, void* d_ws, size_t ws_size,
                              hipStream_t stream) {
    (void)in_sizes; (void)n_in; (void)out_size; (void)ws_size;

    const float* x  = (const float*)d_in[0];
    const float* Wq = (const float*)d_in[1];
    const float* bq = (const float*)d_in[2];
    const float* Wk = (const float*)d_in[3];
    const float* bk = (const float*)d_in[4];
    const float* Wv = (const float*)d_in[5];
    float* out = (float*)d_out;

    unsigned short* xtb = (unsigned short*)d_ws;                    // 16384*1088*2 = 35.7 MB
    unsigned short* gb  = xtb + (size_t)NROWS * HP;                 // 35.7 MB
    unsigned short* vtb = gb  + (size_t)NROWS * HP;                 // 33.6 MB
    unsigned short* pb  = vtb + (size_t)NROWS * H_DIM;              // 128*128*384*2 = 12.6 MB
    unsigned short* wqT = pb  + (size_t)128 * 128 * KB3;            // 2.36 MB
    unsigned short* wkT = wqT + (size_t)WR * H_DIM;                 // 2.36 MB
    unsigned short* p1  = wkT + (size_t)WR * H_DIM;                 // 1152*1088*2 = 2.5 MB
    unsigned short* wvb = p1  + (size_t)WR * HP;                    // 2.1 MB
    // total ~= 127 MB

    prep_small<<<2112, 256, 0, stream>>>(Wq, bq, Wk, bk, Wv, wqT, wkT, wvb, xtb);
    cvtx_p1<<<81 + 8192, 256, 0, stream>>>(x, xtb, wkT, wqT, p1);
    gemm_g<<<9 * 128, 256, 0, stream>>>(xtb, p1, gb);
    pb_vt<<<384 + 1024, 256, 0, stream>>>(gb, xtb, wvb, pb, vtb);
    gemm_out<<<8 * 128, 256, 0, stream>>>(pb, vtb, out);
}